// Round 11
// baseline (855.944 us; speedup 1.0000x reference)
//
#include <hip/hip_runtime.h>
#include <cstdint>
#include <cstddef>

#define BB 256
#define TT 250
#define DIN 700
#define H1 256
#define H2 256
#define DOUT 20
#define BJ0 0.01f
#define BETAC 1.8f
#define IQSCALE 3.814697265625e-06f   // 2^-18

typedef float f32x4 __attribute__((ext_vector_type(4)));
typedef int   i32x4 __attribute__((ext_vector_type(4)));

// ---------------------------------------------------------------------------
// Workspace layout (bytes):
//   Bh   [256*704] i8  @ 0         hi8 of q18(w_i2h1), k-pad 700..703 = 0
//   Bl   [256*704] i8  @ 180224    lo8 (q = 256*hi + lo, exact)
//   sT11 [256*256] s16 @ 360448    sT11[d*256+h] = q18(w_h12h1[h][d])
//   sT12 [256*256] s16 @ 491520    q18(w_h12h2[h][d])
//   sT22 [256*256] s16 @ 622592    q18(w_h22h2[h][d])
//   w2o  [256*20]  f32 @ 753664    w2o[j*20+o] = w_h2o[o][j]
//   Xp   [64000*256] f32 @ 774144
//   Mo   [256*250*20] f32 @ 66310144
// ---------------------------------------------------------------------------
#define COFF_BL  180224
#define SOFF_T11 180224
#define SOFF_T12 245760
#define SOFF_T22 311296
#define FOFF_W2O 188416
#define FOFF_XP  193536
#define FOFF_MO  16577536
#define N_TRANS  381952

// LDS-only drain + raw barrier: all cross-thread traffic in rec_k is LDS
// (lists, counters); global loads/stores stay in flight across barriers.
#define BARRIER_LDS() asm volatile("s_waitcnt lgkmcnt(0)\n\ts_barrier" ::: "memory")

__device__ __forceinline__ short q18(float w) {
    float s = w * 262144.0f;
    s = fminf(fmaxf(s, -32767.0f), 32767.0f);
    return (short)__float2int_rn(s);
}

__global__ void transpose_all_k(const float* __restrict__ w_i2h1,
                                const float* __restrict__ w_h12h1,
                                const float* __restrict__ w_h12h2,
                                const float* __restrict__ w_h22h2,
                                const float* __restrict__ w_h2o,
                                signed char* __restrict__ cws,
                                short* __restrict__ sws,
                                float* __restrict__ fws) {
    int i = blockIdx.x * blockDim.x + threadIdx.x;
    if (i < 180224) {               // Bh/Bl: [h=0..255][k=0..703]
        int h = i / 704, k = i - h * 704;
        int q = (k < DIN) ? (int)q18(w_i2h1[h * DIN + k]) : 0;
        q = q > 32639 ? 32639 : (q < -32640 ? -32640 : q);  // keep hi8 in range
        int hi = (q + 128) >> 8;
        int lo = q - (hi << 8);
        cws[i] = (signed char)hi;
        cws[COFF_BL + i] = (signed char)lo;
        return;
    }
    i -= 180224;
    if (i < 65536) { int d = i >> 8, h = i & 255;
        sws[SOFF_T11 + i] = q18(w_h12h1[h * H1 + d]); return; }
    i -= 65536;
    if (i < 65536) { int d = i >> 8, h = i & 255;
        sws[SOFF_T12 + i] = q18(w_h12h2[h * H1 + d]); return; }
    i -= 65536;
    if (i < 65536) { int d = i >> 8, h = i & 255;
        sws[SOFF_T22 + i] = q18(w_h22h2[h * H2 + d]); return; }
    i -= 65536;
    if (i < 5120)  { int j = i / 20, o = i % 20;
        fws[FOFF_W2O + i] = w_h2o[o * H2 + j]; return; }
}

// ---------------------------------------------------------------------------
// xgemm_k: Xp = x @ W^T + b_h1 via two exact i8 MFMA GEMMs (unchanged).
// ---------------------------------------------------------------------------
__global__ __launch_bounds__(256) void xgemm_k(const float* __restrict__ x,
                                               const signed char* __restrict__ Bh,
                                               const signed char* __restrict__ Bl,
                                               const float* __restrict__ b_h1,
                                               float* __restrict__ Xp) {
    const int t    = threadIdx.x;
    const int lane = t & 63;
    const int w    = t >> 6;             // wave 0..3 -> cols [64w, 64w+64)
    const int m0   = blockIdx.x * 32;

    __shared__ __align__(16) signed char Asub[32 * 720];
    __shared__ __align__(16) signed char Bhs[256 * 80];
    __shared__ __align__(16) signed char Bls[256 * 80];

    #pragma unroll
    for (int it = 0; it < 22; ++it) {
        int flat = it * 256 + t;
        int row  = flat / 176;
        int c4   = flat - row * 176;
        unsigned int pk = 0u;
        if (c4 < 175) {
            const float* xr = x + (size_t)(m0 + row) * DIN;
            float4 f = *(const float4*)(xr + (c4 << 2));
            pk = (f.x != 0.f ? 1u : 0u)
               | (f.y != 0.f ? 1u : 0u) << 8
               | (f.z != 0.f ? 1u : 0u) << 16
               | (f.w != 0.f ? 1u : 0u) << 24;
        }
        *(unsigned int*)(Asub + row * 720 + (c4 << 2)) = pk;
    }

    i32x4 acch[2][4], accl[2][4];
    #pragma unroll
    for (int mt = 0; mt < 2; ++mt)
        #pragma unroll
        for (int nt = 0; nt < 4; ++nt) {
            acch[mt][nt] = (i32x4){0, 0, 0, 0};
            accl[mt][nt] = (i32x4){0, 0, 0, 0};
        }

    const int arow  = lane & 15;
    const int kg16  = (lane >> 4) << 4;
    const int bcol0 = w << 6;

    for (int ks = 0; ks < 11; ++ks) {
        __syncthreads();
        #pragma unroll
        for (int it2 = 0; it2 < 4; ++it2) {
            int row = it2 * 64 + (t >> 2);
            int ch  = (t & 3) << 4;
            int go  = row * 704 + ks * 64 + ch;
            *(int4*)(Bhs + row * 80 + ch) = *(const int4*)(Bh + go);
            *(int4*)(Bls + row * 80 + ch) = *(const int4*)(Bl + go);
        }
        __syncthreads();

        const int ko = ks * 64 + kg16;
        i32x4 a0 = *(const i32x4*)(Asub + arow * 720 + ko);
        i32x4 a1 = *(const i32x4*)(Asub + (16 + arow) * 720 + ko);
        #pragma unroll
        for (int nt = 0; nt < 4; ++nt) {
            const int bb = (bcol0 + nt * 16 + arow) * 80 + kg16;
            i32x4 bhf = *(const i32x4*)(Bhs + bb);
            i32x4 blf = *(const i32x4*)(Bls + bb);
            acch[0][nt] = __builtin_amdgcn_mfma_i32_16x16x64_i8(a0, bhf, acch[0][nt], 0, 0, 0);
            acch[1][nt] = __builtin_amdgcn_mfma_i32_16x16x64_i8(a1, bhf, acch[1][nt], 0, 0, 0);
            accl[0][nt] = __builtin_amdgcn_mfma_i32_16x16x64_i8(a0, blf, accl[0][nt], 0, 0, 0);
            accl[1][nt] = __builtin_amdgcn_mfma_i32_16x16x64_i8(a1, blf, accl[1][nt], 0, 0, 0);
        }
    }

    const int crb = (lane >> 4) << 2;
    #pragma unroll
    for (int nt = 0; nt < 4; ++nt) {
        int col = bcol0 + nt * 16 + arow;
        float bias = b_h1[col];
        #pragma unroll
        for (int mt = 0; mt < 2; ++mt) {
            #pragma unroll
            for (int r = 0; r < 4; ++r) {
                int row = m0 + mt * 16 + crb + r;
                int ir = (acch[mt][nt][r] << 8) + accl[mt][nt][r];
                __builtin_nontemporal_store(bias + (float)ir * IQSCALE,
                                            Xp + (size_t)row * H1 + col);
            }
        }
    }
}

// ---------------------------------------------------------------------------
// Speculative 32-entry gather: list entries 0..31 read and ALL 32 value
// loads issued with ZERO dependence on the count (stale/extra entries are
// always valid rows 0..255 -> safe loads); invalid elements are discarded
// with (tot > j) selects AFTER the values return. The count (LDS read)
// arrives while the loads are in flight -> off the critical path.
// ---------------------------------------------------------------------------
__device__ __forceinline__ int sg32s(const short* __restrict__ T,
                                     const int* __restrict__ L, int tot) {
    int4 e0 = *(const int4*)(L);
    int4 e1 = *(const int4*)(L + 4);
    int4 e2 = *(const int4*)(L + 8);
    int4 e3 = *(const int4*)(L + 12);
    int4 e4 = *(const int4*)(L + 16);
    int4 e5 = *(const int4*)(L + 20);
    int4 e6 = *(const int4*)(L + 24);
    int4 e7 = *(const int4*)(L + 28);
    int w0  = T[e0.x << 8], w1  = T[e0.y << 8], w2  = T[e0.z << 8], w3  = T[e0.w << 8];
    int w4  = T[e1.x << 8], w5  = T[e1.y << 8], w6  = T[e1.z << 8], w7  = T[e1.w << 8];
    int w8  = T[e2.x << 8], w9  = T[e2.y << 8], w10 = T[e2.z << 8], w11 = T[e2.w << 8];
    int w12 = T[e3.x << 8], w13 = T[e3.y << 8], w14 = T[e3.z << 8], w15 = T[e3.w << 8];
    int w16 = T[e4.x << 8], w17 = T[e4.y << 8], w18 = T[e4.z << 8], w19 = T[e4.w << 8];
    int w20 = T[e5.x << 8], w21 = T[e5.y << 8], w22 = T[e5.z << 8], w23 = T[e5.w << 8];
    int w24 = T[e6.x << 8], w25 = T[e6.y << 8], w26 = T[e6.z << 8], w27 = T[e6.w << 8];
    int w28 = T[e7.x << 8], w29 = T[e7.y << 8], w30 = T[e7.z << 8], w31 = T[e7.w << 8];
    int a0 = 0, a1 = 0, a2 = 0, a3 = 0;
    a0 += (tot > 0)  ? w0  : 0;  a1 += (tot > 1)  ? w1  : 0;
    a2 += (tot > 2)  ? w2  : 0;  a3 += (tot > 3)  ? w3  : 0;
    a0 += (tot > 4)  ? w4  : 0;  a1 += (tot > 5)  ? w5  : 0;
    a2 += (tot > 6)  ? w6  : 0;  a3 += (tot > 7)  ? w7  : 0;
    a0 += (tot > 8)  ? w8  : 0;  a1 += (tot > 9)  ? w9  : 0;
    a2 += (tot > 10) ? w10 : 0;  a3 += (tot > 11) ? w11 : 0;
    a0 += (tot > 12) ? w12 : 0;  a1 += (tot > 13) ? w13 : 0;
    a2 += (tot > 14) ? w14 : 0;  a3 += (tot > 15) ? w15 : 0;
    a0 += (tot > 16) ? w16 : 0;  a1 += (tot > 17) ? w17 : 0;
    a2 += (tot > 18) ? w18 : 0;  a3 += (tot > 19) ? w19 : 0;
    a0 += (tot > 20) ? w20 : 0;  a1 += (tot > 21) ? w21 : 0;
    a2 += (tot > 22) ? w22 : 0;  a3 += (tot > 23) ? w23 : 0;
    a0 += (tot > 24) ? w24 : 0;  a1 += (tot > 25) ? w25 : 0;
    a2 += (tot > 26) ? w26 : 0;  a3 += (tot > 27) ? w27 : 0;
    a0 += (tot > 28) ? w28 : 0;  a1 += (tot > 29) ? w29 : 0;
    a2 += (tot > 30) ? w30 : 0;  a3 += (tot > 31) ? w31 : 0;
    return (a0 + a1) + (a2 + a3);
}

__device__ __forceinline__ float sg32f(const float* __restrict__ T,
                                       const int* __restrict__ L, int tot) {
    int4 e0 = *(const int4*)(L);
    int4 e1 = *(const int4*)(L + 4);
    int4 e2 = *(const int4*)(L + 8);
    int4 e3 = *(const int4*)(L + 12);
    int4 e4 = *(const int4*)(L + 16);
    int4 e5 = *(const int4*)(L + 20);
    int4 e6 = *(const int4*)(L + 24);
    int4 e7 = *(const int4*)(L + 28);
    float w0  = T[e0.x * DOUT], w1  = T[e0.y * DOUT], w2  = T[e0.z * DOUT], w3  = T[e0.w * DOUT];
    float w4  = T[e1.x * DOUT], w5  = T[e1.y * DOUT], w6  = T[e1.z * DOUT], w7  = T[e1.w * DOUT];
    float w8  = T[e2.x * DOUT], w9  = T[e2.y * DOUT], w10 = T[e2.z * DOUT], w11 = T[e2.w * DOUT];
    float w12 = T[e3.x * DOUT], w13 = T[e3.y * DOUT], w14 = T[e3.z * DOUT], w15 = T[e3.w * DOUT];
    float w16 = T[e4.x * DOUT], w17 = T[e4.y * DOUT], w18 = T[e4.z * DOUT], w19 = T[e4.w * DOUT];
    float w20 = T[e5.x * DOUT], w21 = T[e5.y * DOUT], w22 = T[e5.z * DOUT], w23 = T[e5.w * DOUT];
    float w24 = T[e6.x * DOUT], w25 = T[e6.y * DOUT], w26 = T[e6.z * DOUT], w27 = T[e6.w * DOUT];
    float w28 = T[e7.x * DOUT], w29 = T[e7.y * DOUT], w30 = T[e7.z * DOUT], w31 = T[e7.w * DOUT];
    float a0 = 0.f, a1 = 0.f, a2 = 0.f, a3 = 0.f;
    a0 += (tot > 0)  ? w0  : 0.f;  a1 += (tot > 1)  ? w1  : 0.f;
    a2 += (tot > 2)  ? w2  : 0.f;  a3 += (tot > 3)  ? w3  : 0.f;
    a0 += (tot > 4)  ? w4  : 0.f;  a1 += (tot > 5)  ? w5  : 0.f;
    a2 += (tot > 6)  ? w6  : 0.f;  a3 += (tot > 7)  ? w7  : 0.f;
    a0 += (tot > 8)  ? w8  : 0.f;  a1 += (tot > 9)  ? w9  : 0.f;
    a2 += (tot > 10) ? w10 : 0.f;  a3 += (tot > 11) ? w11 : 0.f;
    a0 += (tot > 12) ? w12 : 0.f;  a1 += (tot > 13) ? w13 : 0.f;
    a2 += (tot > 14) ? w14 : 0.f;  a3 += (tot > 15) ? w15 : 0.f;
    a0 += (tot > 16) ? w16 : 0.f;  a1 += (tot > 17) ? w17 : 0.f;
    a2 += (tot > 18) ? w18 : 0.f;  a3 += (tot > 19) ? w19 : 0.f;
    a0 += (tot > 20) ? w20 : 0.f;  a1 += (tot > 21) ? w21 : 0.f;
    a2 += (tot > 22) ? w22 : 0.f;  a3 += (tot > 23) ? w23 : 0.f;
    a0 += (tot > 24) ? w24 : 0.f;  a1 += (tot > 25) ? w25 : 0.f;
    a2 += (tot > 26) ? w26 : 0.f;  a3 += (tot > 27) ? w27 : 0.f;
    a0 += (tot > 28) ? w28 : 0.f;  a1 += (tot > 29) ? w29 : 0.f;
    a2 += (tot > 30) ? w30 : 0.f;  a3 += (tot > 31) ? w31 : 0.f;
    return (a0 + a1) + (a2 + a3);
}

// Tail helpers for tot > 32 (rare): 8-wide chunks + count-guarded remainder.
__device__ __forceinline__ void add8s(const short* __restrict__ T,
                                      const int* __restrict__ L, int off,
                                      int& acc) {
    int4 ea = *(const int4*)(L + off);
    int4 eb = *(const int4*)(L + off + 4);
    acc += T[ea.x << 8]; acc += T[ea.y << 8];
    acc += T[ea.z << 8]; acc += T[ea.w << 8];
    acc += T[eb.x << 8]; acc += T[eb.y << 8];
    acc += T[eb.z << 8]; acc += T[eb.w << 8];
}

__device__ __forceinline__ void tails(const short* __restrict__ T,
                                      const int* __restrict__ L, int done,
                                      int rem, int& acc) {
    if (rem >= 4) {
        int4 e = *(const int4*)(L + done);
        acc += T[e.x << 8]; acc += T[e.y << 8];
        acc += T[e.z << 8]; acc += T[e.w << 8];
        done += 4; rem -= 4;
    }
    if (rem) {
        int4 e = *(const int4*)(L + done);
        acc += T[e.x << 8];
        if (rem > 1) acc += T[e.y << 8];
        if (rem > 2) acc += T[e.z << 8];
    }
}

__device__ __forceinline__ void add8f(const float* __restrict__ T,
                                      const int* __restrict__ L, int off,
                                      float& acc) {
    int4 ea = *(const int4*)(L + off);
    int4 eb = *(const int4*)(L + off + 4);
    acc += T[ea.x * DOUT]; acc += T[ea.y * DOUT];
    acc += T[ea.z * DOUT]; acc += T[ea.w * DOUT];
    acc += T[eb.x * DOUT]; acc += T[eb.y * DOUT];
    acc += T[eb.z * DOUT]; acc += T[eb.w * DOUT];
}

__device__ __forceinline__ void tailf(const float* __restrict__ T,
                                      const int* __restrict__ L, int done,
                                      int rem, float& acc) {
    if (rem >= 4) {
        int4 e = *(const int4*)(L + done);
        acc += T[e.x * DOUT]; acc += T[e.y * DOUT];
        acc += T[e.z * DOUT]; acc += T[e.w * DOUT];
        done += 4; rem -= 4;
    }
    if (rem) {
        int4 e = *(const int4*)(L + done);
        acc += T[e.x * DOUT];
        if (rem > 1) acc += T[e.y * DOUT];
        if (rem > 2) acc += T[e.z * DOUT];
    }
}

// ---------------------------------------------------------------------------
// rec_k: R9 protocol (1 barrier/tick, dbuf atomic-compacted lists, rotating
// counters) with SPECULATIVE gathers: the 32-entry head issues immediately
// after the barrier with no dependence on the count; (tot > j) selects
// discard stale elements after the loads return; guarded tail for tot > 32.
// __launch_bounds__(512, 2): true occupancy (2 waves/EU, 1 block/CU by LDS)
// so the allocator keeps all 32 loads in flight behind one waitcnt.
// Element set per sum identical to R9 -> integer spike path bit-exact.
// LDS: 131072 + 20480 + 2*2048 + 32 = 155,680 B (1 block/CU).
// ---------------------------------------------------------------------------
__global__ __launch_bounds__(512, 2) void rec_k(
    const float* __restrict__ Xp,
    const short* __restrict__ sT11, const short* __restrict__ sT12,
    const short* __restrict__ sT22, const float* __restrict__ wT2o,
    const float* __restrict__ b_h2, const float* __restrict__ b_o,
    const float* __restrict__ tau_adp_h1, const float* __restrict__ tau_adp_h2,
    const float* __restrict__ tau_m_h1, const float* __restrict__ tau_m_h2,
    const float* __restrict__ tau_m_o,
    float* __restrict__ Mo) {
    const int tid  = threadIdx.x;        // 0..511
    const int lane = tid & 63;
    const int w    = tid >> 6;           // wave 0..7
    const bool isL1 = (w < 4);
    const int c    = ((w & 3) << 6) + lane;   // owned column within layer
    const int b    = blockIdx.x;
    const float* __restrict__ XpB = Xp + (size_t)b * TT * H1;
    float* __restrict__ MoB = Mo + (size_t)b * TT * DOUT;

    __shared__ __align__(16) short sT22L[65536];   // 128 KB
    __shared__ __align__(16) float w2oL[5120];     // 20 KB  [j][0..19]
    __shared__ __align__(16) int lst1s[2][256];
    __shared__ __align__(16) int lst2s[2][256];
    __shared__ int lcnt[4][2];                     // 4-slot rotation

    // one-time staging
    {
        const int* src = (const int*)sT22;
        int* dst = (int*)sT22L;
        for (int k = tid; k < 32768; k += 512) dst[k] = src[k];
        for (int k = tid; k < 5120; k += 512) w2oL[k] = wT2o[k];
        if (tid < 256) { lst1s[0][tid] = 0; lst1s[1][tid] = 0;
                         lst2s[0][tid] = 0; lst2s[1][tid] = 0; }
        if (tid < 8) ((int*)lcnt)[tid] = 0;
    }

    // per-lane constants (one layer each)
    float alpha, rr, inb = 0.f;
    if (isL1) {
        alpha = expf(-1.0f / tau_m_h1[c]);
        rr    = expf(-1.0f / tau_adp_h1[c]);
    } else {
        alpha = expf(-1.0f / tau_m_h2[c]);
        rr    = expf(-1.0f / tau_adp_h2[c]);
        inb   = b_h2[c];
    }
    const int oc  = ((w & 3) * 5) + lane;          // output col (L1 lanes<5)
    const int ocs = (isL1 && lane < 5) ? oc : 0;
    float alpo = 0.f, bov = 0.f;
    if (isL1 && lane < 5) { alpo = expf(-1.0f / tau_m_o[oc]); bov = b_o[oc]; }

    float mem = 0.f, spk = 0.f, bbv = BJ0;
    float memo = 0.f;

    float xp_cur = 0.f;
    if (isL1) xp_cur = __builtin_nontemporal_load(XpB + c);
    __syncthreads();                       // staging complete (full drain, once)

    for (int i = 0; i <= TT + 1; ++i) {
        const int cur = i & 1, nxt = cur ^ 1;
        const int cc = i & 3, cn = (i + 1) & 3, cz = (i + 2) & 3;

        const int tot1 = lcnt[cc][0];
        const int tot2 = lcnt[cc][1];
        if (tid == 0) { lcnt[cz][0] = 0; lcnt[cz][1] = 0; }

        float xp_nxt = 0.f;
        if (isL1 && i + 1 < TT)
            xp_nxt = __builtin_nontemporal_load(XpB + (size_t)(i + 1) * H1 + c);

        const int* __restrict__ L1l = lst1s[cur];
        const int* __restrict__ L2l = lst2s[cur];

        int acc1 = 0, acc2 = 0;
        float ao = 0.f;

        if (isL1) {
            if (i < TT) {                          // ir11: spec head + rare tail
                const short* colT = sT11 + c;
                acc1 = sg32s(colT, L1l, tot1);
                if (tot1 > 32) {
                    int nb8 = tot1 >> 3;
                    for (int kk = 4; kk < nb8; ++kk) add8s(colT, L1l, kk << 3, acc1);
                    tails(colT, L1l, nb8 << 3, tot1 & 7, acc1);
                }
            }
            if (i >= 2) {                          // output gather (LDS w2o)
                const float* colO = w2oL + ocs;
                ao = sg32f(colO, L2l, tot2);
                if (tot2 > 32) {
                    int nb8 = tot2 >> 3;
                    for (int kk = 4; kk < nb8; ++kk) add8f(colO, L2l, kk << 3, ao);
                    tailf(colO, L2l, nb8 << 3, tot2 & 7, ao);
                }
            }
        } else if (i >= 1 && i <= TT) {
            const short* colT = sT12 + c;
            const short* colL = sT22L + c;
            acc1 = sg32s(colT, L1l, tot1);         // ir12: spec (global)
            acc2 = sg32s(colL, L2l, tot2);         // ir22: spec (LDS)
            if (tot1 > 32) {
                int nb8 = tot1 >> 3;
                for (int kk = 4; kk < nb8; ++kk) add8s(colT, L1l, kk << 3, acc1);
                tails(colT, L1l, nb8 << 3, tot1 & 7, acc1);
            }
            if (tot2 > 32) {
                int nb8 = tot2 >> 3;
                for (int kk = 4; kk < nb8; ++kk) add8s(colL, L2l, kk << 3, acc2);
                tails(colL, L2l, nb8 << 3, tot2 & 7, acc2);
            }
        }

        // ---- update + append (in-registers, per-wave) ----
        if (isL1) {
            if (i < TT) {
                float r1 = (float)acc1 * IQSCALE;
                bbv = rr * bbv + BETAC * (1.f - rr) * spk;
                mem = mem * alpha - bbv * spk + (1.f - alpha) * (xp_cur + r1);
                float ns = (mem - bbv - BJ0) > 0.f ? 1.f : 0.f;
                spk = ns;
                unsigned long long m = __ballot(ns != 0.f ? 1 : 0);
                int base = 0;
                if (lane == 0) base = atomicAdd(&lcnt[cn][0], __popcll(m));
                base = __shfl(base, 0);
                if (ns != 0.f)
                    lst1s[nxt][base + __popcll(m & ((1ull << lane) - 1ull))] = c;
            }
            if (lane < 5 && i >= 2) {
                memo = memo * alpo + (1.f - alpo) * (bov + ao);
                __builtin_nontemporal_store(memo, MoB + (size_t)(i - 2) * DOUT + oc);
            }
        } else if (i >= 1 && i <= TT) {
            float r23 = (float)(acc1 + acc2) * IQSCALE;
            bbv = rr * bbv + BETAC * (1.f - rr) * spk;
            mem = mem * alpha - bbv * spk + (1.f - alpha) * (inb + r23);
            float ns = (mem - bbv - BJ0) > 0.f ? 1.f : 0.f;
            spk = ns;
            unsigned long long m = __ballot(ns != 0.f ? 1 : 0);
            int base = 0;
            if (lane == 0) base = atomicAdd(&lcnt[cn][1], __popcll(m));
            base = __shfl(base, 0);
            if (ns != 0.f)
                lst2s[nxt][base + __popcll(m & ((1ull << lane) - 1ull))] = c;
        }

        BARRIER_LDS();                             // lists + counters published
        xp_cur = xp_nxt;
    }
}

// ---------------------------------------------------------------------------
// soft_k: out[b][h] = Σ_t softmax(Mo[b][t])[h].  One thread per timestep row.
// ---------------------------------------------------------------------------
__global__ __launch_bounds__(256) void soft_k(const float* __restrict__ Mo,
                                              float* __restrict__ out) {
    const int b = blockIdx.x;
    const int t = threadIdx.x;
    __shared__ float sm[TT][DOUT];

    if (t < TT) {
        const float* row = Mo + ((size_t)b * TT + t) * DOUT;
        float v[DOUT];
        #pragma unroll
        for (int k = 0; k < DOUT; k += 4) {
            float4 r = *(const float4*)(row + k);
            v[k] = r.x; v[k + 1] = r.y; v[k + 2] = r.z; v[k + 3] = r.w;
        }
        float mx = v[0];
        #pragma unroll
        for (int j = 1; j < DOUT; ++j) mx = fmaxf(mx, v[j]);
        float s = 0.f;
        #pragma unroll
        for (int j = 0; j < DOUT; ++j) { v[j] = __expf(v[j] - mx); s += v[j]; }
        float inv = 1.0f / s;
        #pragma unroll
        for (int j = 0; j < DOUT; ++j) sm[t][j] = v[j] * inv;
    }
    __syncthreads();
    if (t < DOUT) {
        float acc = 0.f;
        for (int tt = 0; tt < TT; ++tt) acc += sm[tt][t];
        out[b * DOUT + t] = acc;
    }
}

extern "C" void kernel_launch(void* const* d_in, const int* in_sizes, int n_in,
                              void* d_out, int out_size, void* d_ws, size_t ws_size,
                              hipStream_t stream) {
    const float* x          = (const float*)d_in[0];
    const float* w_i2h1     = (const float*)d_in[1];
    const float* w_h12h1    = (const float*)d_in[2];
    const float* w_h12h2    = (const float*)d_in[3];
    const float* w_h22h2    = (const float*)d_in[4];
    const float* w_h2o      = (const float*)d_in[5];
    const float* b_h1       = (const float*)d_in[6];
    const float* b_h2       = (const float*)d_in[7];
    const float* b_o        = (const float*)d_in[8];
    const float* tau_adp_h1 = (const float*)d_in[9];
    const float* tau_adp_h2 = (const float*)d_in[10];
    const float* tau_m_h1   = (const float*)d_in[11];
    const float* tau_m_h2   = (const float*)d_in[12];
    const float* tau_m_o    = (const float*)d_in[13];

    signed char* cws = (signed char*)d_ws;
    short* sws = (short*)d_ws;
    float* fws = (float*)d_ws;
    const signed char* Bh = cws;
    const signed char* Bl = cws + COFF_BL;
    const short* sT11 = sws + SOFF_T11;
    const short* sT12 = sws + SOFF_T12;
    const short* sT22 = sws + SOFF_T22;
    float* wT2o = fws + FOFF_W2O;
    float* Xp   = fws + FOFF_XP;
    float* Mo   = fws + FOFF_MO;

    transpose_all_k<<<N_TRANS / 256, 256, 0, stream>>>(
        w_i2h1, w_h12h1, w_h12h2, w_h22h2, w_h2o, cws, sws, fws);

    xgemm_k<<<(BB * TT) / 32, 256, 0, stream>>>(x, Bh, Bl, b_h1, Xp);

    rec_k<<<BB, 512, 0, stream>>>(Xp, sT11, sT12, sT22, wT2o,
                                  b_h2, b_o, tau_adp_h1, tau_adp_h2,
                                  tau_m_h1, tau_m_h2, tau_m_o, Mo);

    soft_k<<<BB, 256, 0, stream>>>(Mo, (float*)d_out);
}

// Round 12
// 753.481 us; speedup vs baseline: 1.1360x; 1.1360x over previous
//
#include <hip/hip_runtime.h>
#include <cstdint>
#include <cstddef>

#define BB 256
#define TT 250
#define DIN 700
#define H1 256
#define H2 256
#define DOUT 20
#define BJ0 0.01f
#define BETAC 1.8f
#define IQSCALE 3.814697265625e-06f   // 2^-18

typedef float f32x4 __attribute__((ext_vector_type(4)));
typedef short s16x4 __attribute__((ext_vector_type(4)));
typedef int   i32x4 __attribute__((ext_vector_type(4)));

// ---------------------------------------------------------------------------
// Workspace layout (bytes) — identical to R9:
//   Bh   [256*704] i8  @ 0         hi8 of q18(w_i2h1), k-pad 700..703 = 0
//   Bl   [256*704] i8  @ 180224    lo8 (q = 256*hi + lo, exact)
//   sT11 [256*256] s16 @ 360448    sT11[d*256+h] = q18(w_h12h1[h][d])
//   sT12 [256*256] s16 @ 491520    q18(w_h12h2[h][d])
//   sT22 [256*256] s16 @ 622592    q18(w_h22h2[h][d])
//   w2o  [256*20]  f32 @ 753664    w2o[j*20+o] = w_h2o[o][j]
//   Xp   [64000*256] f32 @ 774144
//   Mo   [256*250*20] f32 @ 66310144
// ---------------------------------------------------------------------------
#define COFF_BL  180224
#define SOFF_T11 180224
#define SOFF_T12 245760
#define SOFF_T22 311296
#define FOFF_W2O 188416
#define FOFF_XP  193536
#define FOFF_MO  16577536
#define N_TRANS  381952

// LDS-only drain + raw barrier: all cross-wave traffic in rec_k is LDS
// (lists, counters); global loads/stores stay in flight across barriers.
#define BARRIER_LDS() asm volatile("s_waitcnt lgkmcnt(0)\n\ts_barrier" ::: "memory")

__device__ __forceinline__ short q18(float w) {
    float s = w * 262144.0f;
    s = fminf(fmaxf(s, -32767.0f), 32767.0f);
    return (short)__float2int_rn(s);
}

__global__ void transpose_all_k(const float* __restrict__ w_i2h1,
                                const float* __restrict__ w_h12h1,
                                const float* __restrict__ w_h12h2,
                                const float* __restrict__ w_h22h2,
                                const float* __restrict__ w_h2o,
                                signed char* __restrict__ cws,
                                short* __restrict__ sws,
                                float* __restrict__ fws) {
    int i = blockIdx.x * blockDim.x + threadIdx.x;
    if (i < 180224) {               // Bh/Bl: [h=0..255][k=0..703]
        int h = i / 704, k = i - h * 704;
        int q = (k < DIN) ? (int)q18(w_i2h1[h * DIN + k]) : 0;
        q = q > 32639 ? 32639 : (q < -32640 ? -32640 : q);  // keep hi8 in range
        int hi = (q + 128) >> 8;
        int lo = q - (hi << 8);
        cws[i] = (signed char)hi;
        cws[COFF_BL + i] = (signed char)lo;
        return;
    }
    i -= 180224;
    if (i < 65536) { int d = i >> 8, h = i & 255;
        sws[SOFF_T11 + i] = q18(w_h12h1[h * H1 + d]); return; }
    i -= 65536;
    if (i < 65536) { int d = i >> 8, h = i & 255;
        sws[SOFF_T12 + i] = q18(w_h12h2[h * H1 + d]); return; }
    i -= 65536;
    if (i < 65536) { int d = i >> 8, h = i & 255;
        sws[SOFF_T22 + i] = q18(w_h22h2[h * H2 + d]); return; }
    i -= 65536;
    if (i < 5120)  { int j = i / 20, o = i % 20;
        fws[FOFF_W2O + i] = w_h2o[o * H2 + j]; return; }
}

// ---------------------------------------------------------------------------
// xgemm_k: Xp = x @ W^T + b_h1 via two exact i8 MFMA GEMMs (unchanged).
// ---------------------------------------------------------------------------
__global__ __launch_bounds__(256) void xgemm_k(const float* __restrict__ x,
                                               const signed char* __restrict__ Bh,
                                               const signed char* __restrict__ Bl,
                                               const float* __restrict__ b_h1,
                                               float* __restrict__ Xp) {
    const int t    = threadIdx.x;
    const int lane = t & 63;
    const int w    = t >> 6;             // wave 0..3 -> cols [64w, 64w+64)
    const int m0   = blockIdx.x * 32;

    __shared__ __align__(16) signed char Asub[32 * 720];
    __shared__ __align__(16) signed char Bhs[256 * 80];
    __shared__ __align__(16) signed char Bls[256 * 80];

    #pragma unroll
    for (int it = 0; it < 22; ++it) {
        int flat = it * 256 + t;
        int row  = flat / 176;
        int c4   = flat - row * 176;
        unsigned int pk = 0u;
        if (c4 < 175) {
            const float* xr = x + (size_t)(m0 + row) * DIN;
            float4 f = *(const float4*)(xr + (c4 << 2));
            pk = (f.x != 0.f ? 1u : 0u)
               | (f.y != 0.f ? 1u : 0u) << 8
               | (f.z != 0.f ? 1u : 0u) << 16
               | (f.w != 0.f ? 1u : 0u) << 24;
        }
        *(unsigned int*)(Asub + row * 720 + (c4 << 2)) = pk;
    }

    i32x4 acch[2][4], accl[2][4];
    #pragma unroll
    for (int mt = 0; mt < 2; ++mt)
        #pragma unroll
        for (int nt = 0; nt < 4; ++nt) {
            acch[mt][nt] = (i32x4){0, 0, 0, 0};
            accl[mt][nt] = (i32x4){0, 0, 0, 0};
        }

    const int arow  = lane & 15;
    const int kg16  = (lane >> 4) << 4;
    const int bcol0 = w << 6;

    for (int ks = 0; ks < 11; ++ks) {
        __syncthreads();
        #pragma unroll
        for (int it2 = 0; it2 < 4; ++it2) {
            int row = it2 * 64 + (t >> 2);
            int ch  = (t & 3) << 4;
            int go  = row * 704 + ks * 64 + ch;
            *(int4*)(Bhs + row * 80 + ch) = *(const int4*)(Bh + go);
            *(int4*)(Bls + row * 80 + ch) = *(const int4*)(Bl + go);
        }
        __syncthreads();

        const int ko = ks * 64 + kg16;
        i32x4 a0 = *(const i32x4*)(Asub + arow * 720 + ko);
        i32x4 a1 = *(const i32x4*)(Asub + (16 + arow) * 720 + ko);
        #pragma unroll
        for (int nt = 0; nt < 4; ++nt) {
            const int bb = (bcol0 + nt * 16 + arow) * 80 + kg16;
            i32x4 bhf = *(const i32x4*)(Bhs + bb);
            i32x4 blf = *(const i32x4*)(Bls + bb);
            acch[0][nt] = __builtin_amdgcn_mfma_i32_16x16x64_i8(a0, bhf, acch[0][nt], 0, 0, 0);
            acch[1][nt] = __builtin_amdgcn_mfma_i32_16x16x64_i8(a1, bhf, acch[1][nt], 0, 0, 0);
            accl[0][nt] = __builtin_amdgcn_mfma_i32_16x16x64_i8(a0, blf, accl[0][nt], 0, 0, 0);
            accl[1][nt] = __builtin_amdgcn_mfma_i32_16x16x64_i8(a1, blf, accl[1][nt], 0, 0, 0);
        }
    }

    const int crb = (lane >> 4) << 2;
    #pragma unroll
    for (int nt = 0; nt < 4; ++nt) {
        int col = bcol0 + nt * 16 + arow;
        float bias = b_h1[col];
        #pragma unroll
        for (int mt = 0; mt < 2; ++mt) {
            #pragma unroll
            for (int r = 0; r < 4; ++r) {
                int row = m0 + mt * 16 + crb + r;
                int ir = (acch[mt][nt][r] << 8) + accl[mt][nt][r];
                __builtin_nontemporal_store(bias + (float)ir * IQSCALE,
                                            Xp + (size_t)row * H1 + col);
            }
        }
    }
}

// ---------------------------------------------------------------------------
// 4-column gather helpers: lane owns cols c0..c0+3; per entry e one s16x4
// load at T + e*256 (T pre-offset by c0). 8 entries per wait group;
// count-guarded tail (lists zero-init -> stale int4 reads in-bounds).
// ---------------------------------------------------------------------------
__device__ __forceinline__ void add8v(const short* __restrict__ T,
                                      const int* __restrict__ L, int off,
                                      int* a) {
    int4 ea = *(const int4*)(L + off);
    int4 eb = *(const int4*)(L + off + 4);
    s16x4 w0 = *(const s16x4*)(T + ((size_t)ea.x << 8));
    s16x4 w1 = *(const s16x4*)(T + ((size_t)ea.y << 8));
    s16x4 w2 = *(const s16x4*)(T + ((size_t)ea.z << 8));
    s16x4 w3 = *(const s16x4*)(T + ((size_t)ea.w << 8));
    s16x4 w4 = *(const s16x4*)(T + ((size_t)eb.x << 8));
    s16x4 w5 = *(const s16x4*)(T + ((size_t)eb.y << 8));
    s16x4 w6 = *(const s16x4*)(T + ((size_t)eb.z << 8));
    s16x4 w7 = *(const s16x4*)(T + ((size_t)eb.w << 8));
    a[0] += ((w0.x + w1.x) + (w2.x + w3.x)) + ((w4.x + w5.x) + (w6.x + w7.x));
    a[1] += ((w0.y + w1.y) + (w2.y + w3.y)) + ((w4.y + w5.y) + (w6.y + w7.y));
    a[2] += ((w0.z + w1.z) + (w2.z + w3.z)) + ((w4.z + w5.z) + (w6.z + w7.z));
    a[3] += ((w0.w + w1.w) + (w2.w + w3.w)) + ((w4.w + w5.w) + (w6.w + w7.w));
}

__device__ __forceinline__ void tailv(const short* __restrict__ T,
                                      const int* __restrict__ L, int done,
                                      int rem, int* a) {
    if (rem >= 4) {
        int4 e = *(const int4*)(L + done);
        s16x4 w0 = *(const s16x4*)(T + ((size_t)e.x << 8));
        s16x4 w1 = *(const s16x4*)(T + ((size_t)e.y << 8));
        s16x4 w2 = *(const s16x4*)(T + ((size_t)e.z << 8));
        s16x4 w3 = *(const s16x4*)(T + ((size_t)e.w << 8));
        a[0] += (w0.x + w1.x) + (w2.x + w3.x);
        a[1] += (w0.y + w1.y) + (w2.y + w3.y);
        a[2] += (w0.z + w1.z) + (w2.z + w3.z);
        a[3] += (w0.w + w1.w) + (w2.w + w3.w);
        done += 4; rem -= 4;
    }
    if (rem) {
        int4 e = *(const int4*)(L + done);
        s16x4 w0 = *(const s16x4*)(T + ((size_t)e.x << 8));
        a[0] += w0.x; a[1] += w0.y; a[2] += w0.z; a[3] += w0.w;
        if (rem > 1) {
            s16x4 w1 = *(const s16x4*)(T + ((size_t)e.y << 8));
            a[0] += w1.x; a[1] += w1.y; a[2] += w1.z; a[3] += w1.w;
        }
        if (rem > 2) {
            s16x4 w2 = *(const s16x4*)(T + ((size_t)e.z << 8));
            a[0] += w2.x; a[1] += w2.y; a[2] += w2.z; a[3] += w2.w;
        }
    }
}

__device__ __forceinline__ void add8f(const float* __restrict__ T,
                                      const int* __restrict__ L, int off,
                                      float& acc) {
    int4 ea = *(const int4*)(L + off);
    int4 eb = *(const int4*)(L + off + 4);
    acc += T[ea.x * DOUT]; acc += T[ea.y * DOUT];
    acc += T[ea.z * DOUT]; acc += T[ea.w * DOUT];
    acc += T[eb.x * DOUT]; acc += T[eb.y * DOUT];
    acc += T[eb.z * DOUT]; acc += T[eb.w * DOUT];
}

__device__ __forceinline__ void tailf(const float* __restrict__ T,
                                      const int* __restrict__ L, int done,
                                      int rem, float& acc) {
    if (rem >= 4) {
        int4 e = *(const int4*)(L + done);
        acc += T[e.x * DOUT]; acc += T[e.y * DOUT];
        acc += T[e.z * DOUT]; acc += T[e.w * DOUT];
        done += 4; rem -= 4;
    }
    if (rem) {
        int4 e = *(const int4*)(L + done);
        acc += T[e.x * DOUT];
        if (rem > 1) acc += T[e.y * DOUT];
        if (rem > 2) acc += T[e.z * DOUT];
    }
}

// ---------------------------------------------------------------------------
// rec_k: TWO waves (128 threads). Wave0 = whole L1 layer (lane owns cols
// 4l..4l+3) + output path (lanes 0..19); wave1 = whole L2 layer.
// Per tick (identical offsets to R9): gathers use lst*[cur]/counts[cur];
// updates ballot per column-slot, build lists via INTRA-WAVE PREFIX (no
// atomics, no cross-wave mask merge), plain-store counts. ONE 2-wave
// barrier/tick. All tables read from global (L2-resident); only w2o + lists
// in LDS (~25 KB). Integer q18 sums identical to R9 -> spike path bit-exact.
// ---------------------------------------------------------------------------
__global__ __launch_bounds__(128) void rec_k(
    const float* __restrict__ Xp,
    const short* __restrict__ sT11, const short* __restrict__ sT12,
    const short* __restrict__ sT22, const float* __restrict__ wT2o,
    const float* __restrict__ b_h2, const float* __restrict__ b_o,
    const float* __restrict__ tau_adp_h1, const float* __restrict__ tau_adp_h2,
    const float* __restrict__ tau_m_h1, const float* __restrict__ tau_m_h2,
    const float* __restrict__ tau_m_o,
    float* __restrict__ Mo) {
    const int tid  = threadIdx.x;        // 0..127
    const int lane = tid & 63;
    const int w    = tid >> 6;           // 0 = L1+output, 1 = L2
    const int c0   = lane << 2;          // first of 4 owned columns
    const int b    = blockIdx.x;
    const float* __restrict__ XpB = Xp + (size_t)b * TT * H1;
    float* __restrict__ MoB = Mo + (size_t)b * TT * DOUT;

    __shared__ __align__(16) float w2oL[5120];     // 20 KB [j][0..19]
    __shared__ __align__(16) int lst1s[2][256];
    __shared__ __align__(16) int lst2s[2][256];
    __shared__ int lcnt[2][2];                     // [parity][layer], plain stores

    // one-time staging
    for (int k = tid; k < 5120; k += 128) w2oL[k] = wT2o[k];
    for (int k = tid; k < 256; k += 128) {
        lst1s[0][k] = 0; lst1s[1][k] = 0;
        lst2s[0][k] = 0; lst2s[1][k] = 0;
    }
    if (tid < 4) ((int*)lcnt)[tid] = 0;

    // per-lane constants (4 columns each)
    float alpha[4], rr[4], inb[4];
    #pragma unroll
    for (int s = 0; s < 4; ++s) {
        if (w == 0) {
            alpha[s] = expf(-1.0f / tau_m_h1[c0 + s]);
            rr[s]    = expf(-1.0f / tau_adp_h1[c0 + s]);
            inb[s]   = 0.f;
        } else {
            alpha[s] = expf(-1.0f / tau_m_h2[c0 + s]);
            rr[s]    = expf(-1.0f / tau_adp_h2[c0 + s]);
            inb[s]   = b_h2[c0 + s];
        }
    }
    float alpo = 0.f, bov = 0.f;
    if (w == 0 && lane < DOUT) { alpo = expf(-1.0f / tau_m_o[lane]); bov = b_o[lane]; }

    float mem[4] = {0.f, 0.f, 0.f, 0.f};
    float bb[4]  = {BJ0, BJ0, BJ0, BJ0};
    float spk[4] = {0.f, 0.f, 0.f, 0.f};
    float memo = 0.f;

    f32x4 xp_cur = (f32x4){0.f, 0.f, 0.f, 0.f};
    if (w == 0) xp_cur = *(const f32x4*)(XpB + c0);
    __syncthreads();                       // staging complete (full drain, once)

    for (int i = 0; i <= TT + 1; ++i) {
        const int cur = i & 1, nxt = cur ^ 1;

        const int tot1 = lcnt[cur][0];
        const int tot2 = lcnt[cur][1];

        f32x4 xp_nxt = (f32x4){0.f, 0.f, 0.f, 0.f};
        if (w == 0 && i + 1 < TT)
            xp_nxt = *(const f32x4*)(XpB + (size_t)(i + 1) * H1 + c0);

        const int* __restrict__ L1l = lst1s[cur];
        const int* __restrict__ L2l = lst2s[cur];

        int a1[4] = {0, 0, 0, 0};
        int a2[4] = {0, 0, 0, 0};
        float ao = 0.f;

        if (w == 0) {
            if (i < TT) {                          // ir11: T11 over lst1 (global)
                const short* colT = sT11 + c0;
                const int nb8 = tot1 >> 3;
                for (int kk = 0; kk < nb8; ++kk) add8v(colT, L1l, kk << 3, a1);
                tailv(colT, L1l, nb8 << 3, tot1 & 7, a1);
            }
            if (lane < DOUT && i >= 2) {           // output: w2o over lst2 (LDS)
                const float* colO = w2oL + lane;
                const int nb8 = tot2 >> 3;
                for (int kk = 0; kk < nb8; ++kk) add8f(colO, L2l, kk << 3, ao);
                tailf(colO, L2l, nb8 << 3, tot2 & 7, ao);
            }
        } else if (i >= 1 && i <= TT) {            // ir12 + ir22, interleaved
            const short* cT12 = sT12 + c0;
            const short* cT22 = sT22 + c0;
            const int nb81 = tot1 >> 3;
            const int nb82 = tot2 >> 3;
            const int nbm = nb81 > nb82 ? nb81 : nb82;
            for (int kk = 0; kk < nbm; ++kk) {
                if (kk < nb81) add8v(cT12, L1l, kk << 3, a1);
                if (kk < nb82) add8v(cT22, L2l, kk << 3, a2);
            }
            tailv(cT12, L1l, nb81 << 3, tot1 & 7, a1);
            tailv(cT22, L2l, nb82 << 3, tot2 & 7, a2);
        }

        // ---- update + list build (intra-wave prefix, plain-store counts) ----
        if (w == 0) {
            int tot = 0;
            if (i < TT) {
                unsigned long long Ms[4];
                #pragma unroll
                for (int s = 0; s < 4; ++s) {
                    float r1 = (float)a1[s] * IQSCALE;
                    bb[s]  = rr[s] * bb[s] + BETAC * (1.f - rr[s]) * spk[s];
                    mem[s] = mem[s] * alpha[s] - bb[s] * spk[s]
                           + (1.f - alpha[s]) * (xp_cur[s] + r1);
                    float ns = (mem[s] - bb[s] - BJ0) > 0.f ? 1.f : 0.f;
                    spk[s] = ns;
                    Ms[s] = __ballot(ns != 0.f ? 1 : 0);
                }
                const unsigned long long below = (1ull << lane) - 1ull;
                int p0 = __popcll(Ms[0]), p1 = __popcll(Ms[1]);
                int p2 = __popcll(Ms[2]), p3 = __popcll(Ms[3]);
                int b1 = p0, b2 = p0 + p1, b3 = p0 + p1 + p2;
                tot = b3 + p3;
                if (spk[0] != 0.f) lst1s[nxt][__popcll(Ms[0] & below)]      = c0;
                if (spk[1] != 0.f) lst1s[nxt][b1 + __popcll(Ms[1] & below)] = c0 + 1;
                if (spk[2] != 0.f) lst1s[nxt][b2 + __popcll(Ms[2] & below)] = c0 + 2;
                if (spk[3] != 0.f) lst1s[nxt][b3 + __popcll(Ms[3] & below)] = c0 + 3;
            }
            if (lane == 0) lcnt[nxt][0] = tot;
            if (lane < DOUT && i >= 2) {
                memo = memo * alpo + (1.f - alpo) * (bov + ao);
                __builtin_nontemporal_store(memo, MoB + (size_t)(i - 2) * DOUT + lane);
            }
        } else {
            int tot = 0;
            if (i >= 1 && i <= TT) {
                unsigned long long Ms[4];
                #pragma unroll
                for (int s = 0; s < 4; ++s) {
                    float r23 = (float)(a1[s] + a2[s]) * IQSCALE;
                    bb[s]  = rr[s] * bb[s] + BETAC * (1.f - rr[s]) * spk[s];
                    mem[s] = mem[s] * alpha[s] - bb[s] * spk[s]
                           + (1.f - alpha[s]) * (inb[s] + r23);
                    float ns = (mem[s] - bb[s] - BJ0) > 0.f ? 1.f : 0.f;
                    spk[s] = ns;
                    Ms[s] = __ballot(ns != 0.f ? 1 : 0);
                }
                const unsigned long long below = (1ull << lane) - 1ull;
                int p0 = __popcll(Ms[0]), p1 = __popcll(Ms[1]);
                int p2 = __popcll(Ms[2]), p3 = __popcll(Ms[3]);
                int b1 = p0, b2 = p0 + p1, b3 = p0 + p1 + p2;
                tot = b3 + p3;
                if (spk[0] != 0.f) lst2s[nxt][__popcll(Ms[0] & below)]      = c0;
                if (spk[1] != 0.f) lst2s[nxt][b1 + __popcll(Ms[1] & below)] = c0 + 1;
                if (spk[2] != 0.f) lst2s[nxt][b2 + __popcll(Ms[2] & below)] = c0 + 2;
                if (spk[3] != 0.f) lst2s[nxt][b3 + __popcll(Ms[3] & below)] = c0 + 3;
            }
            if (lane == 0) lcnt[nxt][1] = tot;
        }

        BARRIER_LDS();                             // lists + counters published
        xp_cur = xp_nxt;
    }
}

// ---------------------------------------------------------------------------
// soft_k: out[b][h] = Σ_t softmax(Mo[b][t])[h].  One thread per timestep row.
// ---------------------------------------------------------------------------
__global__ __launch_bounds__(256) void soft_k(const float* __restrict__ Mo,
                                              float* __restrict__ out) {
    const int b = blockIdx.x;
    const int t = threadIdx.x;
    __shared__ float sm[TT][DOUT];

    if (t < TT) {
        const float* row = Mo + ((size_t)b * TT + t) * DOUT;
        float v[DOUT];
        #pragma unroll
        for (int k = 0; k < DOUT; k += 4) {
            float4 r = *(const float4*)(row + k);
            v[k] = r.x; v[k + 1] = r.y; v[k + 2] = r.z; v[k + 3] = r.w;
        }
        float mx = v[0];
        #pragma unroll
        for (int j = 1; j < DOUT; ++j) mx = fmaxf(mx, v[j]);
        float s = 0.f;
        #pragma unroll
        for (int j = 0; j < DOUT; ++j) { v[j] = __expf(v[j] - mx); s += v[j]; }
        float inv = 1.0f / s;
        #pragma unroll
        for (int j = 0; j < DOUT; ++j) sm[t][j] = v[j] * inv;
    }
    __syncthreads();
    if (t < DOUT) {
        float acc = 0.f;
        for (int tt = 0; tt < TT; ++tt) acc += sm[tt][t];
        out[b * DOUT + t] = acc;
    }
}

extern "C" void kernel_launch(void* const* d_in, const int* in_sizes, int n_in,
                              void* d_out, int out_size, void* d_ws, size_t ws_size,
                              hipStream_t stream) {
    const float* x          = (const float*)d_in[0];
    const float* w_i2h1     = (const float*)d_in[1];
    const float* w_h12h1    = (const float*)d_in[2];
    const float* w_h12h2    = (const float*)d_in[3];
    const float* w_h22h2    = (const float*)d_in[4];
    const float* w_h2o      = (const float*)d_in[5];
    const float* b_h1       = (const float*)d_in[6];
    const float* b_h2       = (const float*)d_in[7];
    const float* b_o        = (const float*)d_in[8];
    const float* tau_adp_h1 = (const float*)d_in[9];
    const float* tau_adp_h2 = (const float*)d_in[10];
    const float* tau_m_h1   = (const float*)d_in[11];
    const float* tau_m_h2   = (const float*)d_in[12];
    const float* tau_m_o    = (const float*)d_in[13];

    signed char* cws = (signed char*)d_ws;
    short* sws = (short*)d_ws;
    float* fws = (float*)d_ws;
    const signed char* Bh = cws;
    const signed char* Bl = cws + COFF_BL;
    const short* sT11 = sws + SOFF_T11;
    const short* sT12 = sws + SOFF_T12;
    const short* sT22 = sws + SOFF_T22;
    float* wT2o = fws + FOFF_W2O;
    float* Xp   = fws + FOFF_XP;
    float* Mo   = fws + FOFF_MO;

    transpose_all_k<<<N_TRANS / 256, 256, 0, stream>>>(
        w_i2h1, w_h12h1, w_h12h2, w_h22h2, w_h2o, cws, sws, fws);

    xgemm_k<<<(BB * TT) / 32, 256, 0, stream>>>(x, Bh, Bl, b_h1, Xp);

    rec_k<<<BB, 128, 0, stream>>>(Xp, sT11, sT12, sT22, wT2o,
                                  b_h2, b_o, tau_adp_h1, tau_adp_h2,
                                  tau_m_h1, tau_m_h2, tau_m_o, Mo);

    soft_k<<<BB, 256, 0, stream>>>(Mo, (float*)d_out);
}